// Round 1
// baseline (46.542 us; speedup 1.0000x reference)
//
#include <hip/hip_runtime.h>
#include <math.h>

// histogram_binning_calibration: logits [32768,1000] f32, histogram [15] f32
// outputs (concat flat, f32): sm_calib [N*C], valid_flag [N], pred [N]

constexpr int N_EX    = 32768;
constexpr int N_CLS   = 1000;
constexpr int N_BINS  = 15;
constexpr int C4      = N_CLS / 4;   // 250 float4 per row

__global__ __launch_bounds__(256) void hb_calib_kernel(
    const float* __restrict__ logits,
    const float* __restrict__ hist,
    float* __restrict__ out)
{
    const int wave = threadIdx.x >> 6;          // 0..3
    const int lane = threadIdx.x & 63;
    const int row  = blockIdx.x * 4 + wave;
    if (row >= N_EX) return;

    const float4* lrow = reinterpret_cast<const float4*>(logits + (size_t)row * N_CLS);

    // ---- pass over registers: load 16 floats/lane, track local max + first index
    float4 v[4];
    float lmax = -INFINITY;
    int   lidx = N_CLS;                         // larger than any valid col
    #pragma unroll
    for (int r = 0; r < 4; ++r) {
        const int q = lane + 64 * r;
        if (q < C4) {
            v[r] = lrow[q];
            float* f = reinterpret_cast<float*>(&v[r]);
            #pragma unroll
            for (int t = 0; t < 4; ++t) {
                const int col = 4 * q + t;
                const float x = f[t];
                if (x > lmax) { lmax = x; lidx = col; }
            }
        }
    }

    // ---- wave butterfly reduce: (max, smallest index achieving max)
    float m   = lmax;
    int   mix = lidx;
    #pragma unroll
    for (int off = 32; off >= 1; off >>= 1) {
        const float ov = __shfl_xor(m, off);
        const int   oi = __shfl_xor(mix, off);
        if (ov > m || (ov == m && oi < mix)) { m = ov; mix = oi; }
    }

    // ---- exp in place, sum excluding the argmax position
    float lsum = 0.0f;
    #pragma unroll
    for (int r = 0; r < 4; ++r) {
        const int q = lane + 64 * r;
        if (q < C4) {
            float* f = reinterpret_cast<float*>(&v[r]);
            #pragma unroll
            for (int t = 0; t < 4; ++t) {
                const int col = 4 * q + t;
                const float e = __expf(f[t] - m);
                f[t] = e;
                if (col != mix) lsum += e;
            }
        }
    }
    float srest = lsum;
    #pragma unroll
    for (int off = 32; off >= 1; off >>= 1) srest += __shfl_xor(srest, off);

    const float s    = srest + 1.0f;            // full softmax denominator
    const float conf = 1.0f / s;                // max softmax value

    // ---- histogram bin lookup: (lower, upper] bins -> ceil(conf*15)-1
    int bin = (int)ceilf(conf * (float)N_BINS) - 1;
    bin = bin < 0 ? 0 : (bin > N_BINS - 1 ? N_BINS - 1 : bin);
    const float h     = hist[bin];
    const float valid = (h != -1.0f) ? 1.0f : 0.0f;
    const float est   = (h == -1.0f) ? conf : h;

    // rescaled_j = (1-est) * sm_j / denom ; denom = srest/s ; sm_j = e_j/s
    //           => e_j * (1-est)/srest.  Final renorm == 1 to fp rounding.
    const float scale = (1.0f - est) / srest;

    // ---- write calibrated softmax, coalesced float4
    float4* orow = reinterpret_cast<float4*>(out + (size_t)row * N_CLS);
    #pragma unroll
    for (int r = 0; r < 4; ++r) {
        const int q = lane + 64 * r;
        if (q < C4) {
            float* f = reinterpret_cast<float*>(&v[r]);
            float4 o;
            float* of = reinterpret_cast<float*>(&o);
            #pragma unroll
            for (int t = 0; t < 4; ++t) {
                const int col = 4 * q + t;
                of[t] = (col == mix) ? est : f[t] * scale;
            }
            orow[q] = o;
        }
    }

    // ---- tail outputs: valid_flag [N], pred [N] (as float)
    if (lane == 0) {
        const size_t base = (size_t)N_EX * N_CLS;
        out[base + row]        = valid;
        out[base + N_EX + row] = (float)mix;
    }
}

extern "C" void kernel_launch(void* const* d_in, const int* in_sizes, int n_in,
                              void* d_out, int out_size, void* d_ws, size_t ws_size,
                              hipStream_t stream) {
    const float* logits = (const float*)d_in[0];
    const float* hist   = (const float*)d_in[1];
    float* out          = (float*)d_out;

    const int rows_per_block = 4;                       // 4 waves * 1 row each
    const int grid = (N_EX + rows_per_block - 1) / rows_per_block;  // 8192
    hb_calib_kernel<<<grid, 256, 0, stream>>>(logits, hist, out);
}

// Round 3
// 44.523 us; speedup vs baseline: 1.0453x; 1.0453x over previous
//
#include <hip/hip_runtime.h>
#include <math.h>

// histogram_binning_calibration: logits [32768,1000] f32, histogram [15] f32
// outputs (concat flat, f32): sm_calib [N*C], valid_flag [N], pred [N]

constexpr int N_EX    = 32768;
constexpr int N_CLS   = 1000;
constexpr int N_BINS  = 15;
constexpr int C4      = N_CLS / 4;   // 250 float4 per row

typedef float vf4 __attribute__((ext_vector_type(4)));  // clang vector: nt-store OK

__global__ __launch_bounds__(256) void hb_calib_kernel(
    const float* __restrict__ logits,
    const float* __restrict__ hist,
    float* __restrict__ out)
{
    const int wave = threadIdx.x >> 6;          // 0..3
    const int lane = threadIdx.x & 63;
    const int row  = blockIdx.x * 4 + wave;

    const vf4* lrow = reinterpret_cast<const vf4*>(logits + (size_t)row * N_CLS);

    // ---- unconditional clamped loads: all 4 dwordx4 issue up front
    vf4 v[4];
    #pragma unroll
    for (int r = 0; r < 4; ++r) {
        const int q  = lane + 64 * r;
        const int ql = (q < C4) ? q : (C4 - 1);
        v[r] = lrow[ql];
    }

    // ---- local max + first index (skip duplicated tail lanes)
    float lmax = -INFINITY;
    int   lidx = N_CLS;
    #pragma unroll
    for (int r = 0; r < 4; ++r) {
        const int q = lane + 64 * r;
        if (q < C4) {
            #pragma unroll
            for (int t = 0; t < 4; ++t) {
                const int col = 4 * q + t;
                const float x = v[r][t];
                if (x > lmax) { lmax = x; lidx = col; }
            }
        }
    }

    // ---- wave butterfly reduce: (max, smallest index achieving max)
    float m   = lmax;
    int   mix = lidx;
    #pragma unroll
    for (int off = 32; off >= 1; off >>= 1) {
        const float ov = __shfl_xor(m, off);
        const int   oi = __shfl_xor(mix, off);
        if (ov > m || (ov == m && oi < mix)) { m = ov; mix = oi; }
    }

    // ---- exp in place, sum ALL (e_argmax == exp(0) == 1 exactly)
    float lsum = 0.0f;
    #pragma unroll
    for (int r = 0; r < 4; ++r) {
        const int q = lane + 64 * r;
        if (q < C4) {
            #pragma unroll
            for (int t = 0; t < 4; ++t) {
                const float e = __expf(v[r][t] - m);
                v[r][t] = e;
                lsum += e;
            }
        }
    }
    float s = lsum;
    #pragma unroll
    for (int off = 32; off >= 1; off >>= 1) s += __shfl_xor(s, off);

    const float srest = s - 1.0f;               // mass excluding argmax
    const float conf  = 1.0f / s;               // max softmax value

    // ---- histogram bin lookup: (lower, upper] bins -> ceil(conf*15)-1
    int bin = (int)ceilf(conf * (float)N_BINS) - 1;
    bin = bin < 0 ? 0 : (bin > N_BINS - 1 ? N_BINS - 1 : bin);
    const float h     = hist[bin];
    const float valid = (h != -1.0f) ? 1.0f : 0.0f;
    const float est   = (h == -1.0f) ? conf : h;

    // rescaled_j = e_j * (1-est)/srest ; argmax entry = est
    const float scale = (1.0f - est) / srest;

    // ---- write calibrated softmax, coalesced nontemporal float4
    vf4* orow = reinterpret_cast<vf4*>(out + (size_t)row * N_CLS);
    #pragma unroll
    for (int r = 0; r < 4; ++r) {
        const int q = lane + 64 * r;
        if (q < C4) {
            vf4 o;
            #pragma unroll
            for (int t = 0; t < 4; ++t) {
                const int col = 4 * q + t;
                o[t] = (col == mix) ? est : v[r][t] * scale;
            }
            __builtin_nontemporal_store(o, &orow[q]);
        }
    }

    // ---- tail outputs: valid_flag [N], pred [N] (as float)
    if (lane == 0) {
        const size_t base = (size_t)N_EX * N_CLS;
        __builtin_nontemporal_store(valid, &out[base + row]);
        __builtin_nontemporal_store((float)mix, &out[base + N_EX + row]);
    }
}

extern "C" void kernel_launch(void* const* d_in, const int* in_sizes, int n_in,
                              void* d_out, int out_size, void* d_ws, size_t ws_size,
                              hipStream_t stream) {
    const float* logits = (const float*)d_in[0];
    const float* hist   = (const float*)d_in[1];
    float* out          = (float*)d_out;

    const int rows_per_block = 4;                       // 4 waves * 1 row each
    const int grid = (N_EX + rows_per_block - 1) / rows_per_block;  // 8192
    hb_calib_kernel<<<grid, 256, 0, stream>>>(logits, hist, out);
}

// Round 4
// 44.412 us; speedup vs baseline: 1.0480x; 1.0025x over previous
//
#include <hip/hip_runtime.h>
#include <math.h>

// histogram_binning_calibration: logits [32768,1000] f32, histogram [15] f32
// outputs (concat flat, f32): sm_calib [N*C], valid_flag [N], pred [N]

constexpr int N_EX    = 32768;
constexpr int N_CLS   = 1000;
constexpr int N_BINS  = 15;
constexpr int C4      = N_CLS / 4;   // 250 float4 per row

typedef float vf4 __attribute__((ext_vector_type(4)));

__global__ __launch_bounds__(256) void hb_calib_kernel(
    const float* __restrict__ logits,
    const float* __restrict__ hist,
    float* __restrict__ out)
{
    const int wave = threadIdx.x >> 6;          // 0..3
    const int lane = threadIdx.x & 63;
    const int row0 = (blockIdx.x * 4 + wave) * 2;   // this wave: rows row0, row0+1

    const vf4* lrowA = reinterpret_cast<const vf4*>(logits + (size_t)row0 * N_CLS);
    const vf4* lrowB = reinterpret_cast<const vf4*>(logits + (size_t)(row0 + 1) * N_CLS);

    // ---- issue ALL 8 dwordx4 loads up front (2 rows in flight)
    vf4 va[4], vb[4];
    #pragma unroll
    for (int r = 0; r < 4; ++r) {
        const int q  = lane + 64 * r;
        const int ql = (q < C4) ? q : (C4 - 1);
        va[r] = lrowA[ql];
        vb[r] = lrowB[ql];
    }

    // ---- local max + first index, both rows
    float ma = -INFINITY, mb = -INFINITY;
    int   ia = N_CLS,     ib = N_CLS;
    #pragma unroll
    for (int r = 0; r < 4; ++r) {
        const int q = lane + 64 * r;
        if (q < C4) {
            #pragma unroll
            for (int t = 0; t < 4; ++t) {
                const int col = 4 * q + t;
                const float xa = va[r][t];
                const float xb = vb[r][t];
                if (xa > ma) { ma = xa; ia = col; }
                if (xb > mb) { mb = xb; ib = col; }
            }
        }
    }

    // ---- interleaved butterfly reduce: two independent (max, first-idx) chains
    #pragma unroll
    for (int off = 32; off >= 1; off >>= 1) {
        const float ova = __shfl_xor(ma, off);
        const int   oia = __shfl_xor(ia, off);
        const float ovb = __shfl_xor(mb, off);
        const int   oib = __shfl_xor(ib, off);
        if (ova > ma || (ova == ma && oia < ia)) { ma = ova; ia = oia; }
        if (ovb > mb || (ovb == mb && oib < ib)) { mb = ovb; ib = oib; }
    }

    // ---- exp in place, sum ALL (e_argmax == exp(0) == 1 exactly), both rows
    float sa = 0.0f, sb = 0.0f;
    #pragma unroll
    for (int r = 0; r < 4; ++r) {
        const int q = lane + 64 * r;
        if (q < C4) {
            #pragma unroll
            for (int t = 0; t < 4; ++t) {
                const float ea = __expf(va[r][t] - ma);
                const float eb = __expf(vb[r][t] - mb);
                va[r][t] = ea;
                vb[r][t] = eb;
                sa += ea;
                sb += eb;
            }
        }
    }
    #pragma unroll
    for (int off = 32; off >= 1; off >>= 1) {
        sa += __shfl_xor(sa, off);
        sb += __shfl_xor(sb, off);
    }

    // ---- per-row epilogue scalars
    const float confA = 1.0f / sa;
    const float confB = 1.0f / sb;

    int binA = (int)ceilf(confA * (float)N_BINS) - 1;
    int binB = (int)ceilf(confB * (float)N_BINS) - 1;
    binA = binA < 0 ? 0 : (binA > N_BINS - 1 ? N_BINS - 1 : binA);
    binB = binB < 0 ? 0 : (binB > N_BINS - 1 ? N_BINS - 1 : binB);
    const float hA = hist[binA];
    const float hB = hist[binB];
    const float validA = (hA != -1.0f) ? 1.0f : 0.0f;
    const float validB = (hB != -1.0f) ? 1.0f : 0.0f;
    const float estA = (hA == -1.0f) ? confA : hA;
    const float estB = (hB == -1.0f) ? confB : hB;
    const float scaleA = (1.0f - estA) / (sa - 1.0f);
    const float scaleB = (1.0f - estB) / (sb - 1.0f);

    // ---- write calibrated softmax, coalesced nontemporal dwordx4, both rows
    vf4* orowA = reinterpret_cast<vf4*>(out + (size_t)row0 * N_CLS);
    vf4* orowB = reinterpret_cast<vf4*>(out + (size_t)(row0 + 1) * N_CLS);
    #pragma unroll
    for (int r = 0; r < 4; ++r) {
        const int q = lane + 64 * r;
        if (q < C4) {
            vf4 oa, ob;
            #pragma unroll
            for (int t = 0; t < 4; ++t) {
                const int col = 4 * q + t;
                oa[t] = (col == ia) ? estA : va[r][t] * scaleA;
                ob[t] = (col == ib) ? estB : vb[r][t] * scaleB;
            }
            __builtin_nontemporal_store(oa, &orowA[q]);
            __builtin_nontemporal_store(ob, &orowB[q]);
        }
    }

    // ---- tail outputs: valid_flag [N], pred [N] (as float)
    if (lane == 0) {
        const size_t base = (size_t)N_EX * N_CLS;
        __builtin_nontemporal_store(validA, &out[base + row0]);
        __builtin_nontemporal_store(validB, &out[base + row0 + 1]);
        __builtin_nontemporal_store((float)ia, &out[base + N_EX + row0]);
        __builtin_nontemporal_store((float)ib, &out[base + N_EX + row0 + 1]);
    }
}

extern "C" void kernel_launch(void* const* d_in, const int* in_sizes, int n_in,
                              void* d_out, int out_size, void* d_ws, size_t ws_size,
                              hipStream_t stream) {
    const float* logits = (const float*)d_in[0];
    const float* hist   = (const float*)d_in[1];
    float* out          = (float*)d_out;

    const int rows_per_block = 8;                       // 4 waves * 2 rows each
    const int grid = (N_EX + rows_per_block - 1) / rows_per_block;  // 4096
    hb_calib_kernel<<<grid, 256, 0, stream>>>(logits, hist, out);
}